// Round 1
// baseline (373.508 us; speedup 1.0000x reference)
//
#include <hip/hip_runtime.h>

// ---------------------------------------------------------------------------
// PGAConjugateLinear:  out[b,o,p] = sum_{i,r} Wmat[o,i,p,r] * xin[b,i,r]
//   Wmat[o,i] = weight[o,i] * (A(rev(k)) @ Bm(k))[3x4], k = action embedded
//   xin[b,i]  = (x[b,i,0], x[b,i,1], x[b,i,2], embed_e0[i])
// Stage 1 builds Wmat in B^T layout Bw[n=o*3+p][k=i*4+r]  (12.6 MB in d_ws).
// Stage 2 is a 64x64x16 LDS-tiled fp32 GEMM  (M=4096, N=1536, K=2048).
// ---------------------------------------------------------------------------

#define B_DIM 4096
#define I_DIM 512
#define O_DIM 512
#define N_DIM (O_DIM * 3)   // 1536
#define K_DIM (I_DIM * 4)   // 2048

// Cayley table for Cl(3,0,1), metric [0,1,1,1], blade order = reference order.
struct Cayley {
    float M[16][16][16];
    float rev[16];
    constexpr Cayley() : M{}, rev{} {
        // blade bitmasks in the reference's (grade-major, lex) order
        const unsigned masks[16] = {0u,
                                    1u, 2u, 4u, 8u,
                                    3u, 5u, 9u, 6u, 10u, 12u,
                                    7u, 11u, 13u, 14u,
                                    15u};
        int idx_of[16] = {};
        for (int i = 0; i < 16; ++i) idx_of[masks[i]] = i;
        const int metric[4] = {0, 1, 1, 1};
        for (int i = 0; i < 16; ++i) {
            unsigned a = masks[i];
            for (int j = 0; j < 16; ++j) {
                unsigned b = masks[j];
                int swaps = 0;  // inversions between sorted lists a,b
                for (int jb = 0; jb < 4; ++jb)
                    if ((b >> jb) & 1u)
                        for (int ia = jb + 1; ia < 4; ++ia)
                            if ((a >> ia) & 1u) ++swaps;
                int sign = (swaps & 1) ? -1 : 1;
                unsigned common = a & b;
                for (int g = 0; g < 4; ++g)
                    if ((common >> g) & 1u) sign *= metric[g];
                if (sign != 0) M[i][j][idx_of[a ^ b]] += (float)sign;
            }
            int grade = 0;
            for (int g = 0; g < 4; ++g) grade += (int)((a >> g) & 1u);
            rev[i] = ((grade * (grade - 1) / 2) % 2) ? -1.f : 1.f;
        }
    }
};
constexpr Cayley CAY{};

// ---------------------------------------------------------------------------
// Stage 1: Bw[(o*3+p)*K_DIM + i*4 + r] = weight[o,i] * T[p][r]
// One thread per (o,i). All Cayley indices are compile-time constants after
// unrolling, so CAY.M folds to the sparse +-1 pattern (no table in memory).
// ---------------------------------------------------------------------------
__global__ __launch_bounds__(256) void build_w(const float* __restrict__ weight,
                                               const float* __restrict__ action,
                                               float* __restrict__ Bw) {
    const int t = blockIdx.x * 256 + threadIdx.x;   // t = o*512 + i
    const int o = t >> 9;
    const int i = t & 511;

    float a[8];
    const float* ap = action + (size_t)t * 8;
#pragma unroll
    for (int j = 0; j < 8; ++j) a[j] = ap[j];

    float kv[16], kr[16];
#pragma unroll
    for (int j = 0; j < 16; ++j) { kv[j] = 0.f; kr[j] = 0.f; }
    constexpr int AB[8] = {0, 5, 6, 7, 8, 9, 10, 15};
#pragma unroll
    for (int j = 0; j < 8; ++j) {
        kv[AB[j]] = a[j];
        kr[AB[j]] = a[j] * CAY.rev[AB[j]];
    }

    constexpr int PB[3] = {11, 12, 13};
    constexpr int RB[4] = {11, 12, 13, 14};

    // Am[p][q] = sum_t M[q][PB[p]][t] * kr[t]      (k_r factor)
    float Am[3][16];
#pragma unroll
    for (int pp = 0; pp < 3; ++pp)
#pragma unroll
        for (int q = 0; q < 16; ++q) {
            float s = 0.f;
#pragma unroll
            for (int tt = 0; tt < 16; ++tt) s += CAY.M[q][PB[pp]][tt] * kr[tt];
            Am[pp][q] = s;
        }

    // Bm[q][r] = sum_m M[m][q][RB[r]] * kv[m]      (k_l factor)
    float Bm[16][4];
#pragma unroll
    for (int q = 0; q < 16; ++q)
#pragma unroll
        for (int rr = 0; rr < 4; ++rr) {
            float s = 0.f;
#pragma unroll
            for (int m = 0; m < 16; ++m) s += CAY.M[m][q][RB[rr]] * kv[m];
            Bm[q][rr] = s;
        }

    const float w = weight[t];
#pragma unroll
    for (int pp = 0; pp < 3; ++pp) {
        float r0 = 0.f, r1 = 0.f, r2 = 0.f, r3 = 0.f;
#pragma unroll
        for (int q = 0; q < 16; ++q) {
            r0 += Am[pp][q] * Bm[q][0];
            r1 += Am[pp][q] * Bm[q][1];
            r2 += Am[pp][q] * Bm[q][2];
            r3 += Am[pp][q] * Bm[q][3];
        }
        float4 o4 = make_float4(w * r0, w * r1, w * r2, w * r3);
        *(float4*)(Bw + (size_t)(o * 3 + pp) * K_DIM + i * 4) = o4;  // coalesced
    }
}

// ---------------------------------------------------------------------------
// Stage 2: C[m][n] = sum_k A[m][k] * Bw[n][k]
//   A[m][k] built on the fly: k = i*4+r, r<3 -> x[m][i][r], r==3 -> e0[i]
// 64x64 tile, BK=16, 256 threads, 4x4 per-thread micro-tile.
// ---------------------------------------------------------------------------
__global__ __launch_bounds__(256) void gemm_f32(const float* __restrict__ x,
                                                const float* __restrict__ e0,
                                                const float* __restrict__ Bw,
                                                float* __restrict__ C) {
    __shared__ float As[16][64];
    __shared__ float Bs[16][64];

    const int tid = threadIdx.x;
    const int tx = tid & 15, ty = tid >> 4;
    const int m0 = blockIdx.y * 64, n0 = blockIdx.x * 64;
    const int row = tid >> 2, kq = tid & 3;   // staging assignment

    const float* xrow = x + (size_t)(m0 + row) * (I_DIM * 3);
    const float* brow = Bw + (size_t)(n0 + row) * K_DIM;

    float acc[4][4] = {{0.f}};

    for (int k0 = 0; k0 < K_DIM; k0 += 16) {
        const int i = (k0 >> 2) + kq;  // this thread's input-channel index
        const float vx = xrow[i * 3 + 0];
        const float vy = xrow[i * 3 + 1];
        const float vz = xrow[i * 3 + 2];
        const float ve = e0[i];
        const float4 bv = *(const float4*)(brow + k0 + kq * 4);

        __syncthreads();  // previous iteration's compute done before overwrite
        As[kq * 4 + 0][row] = vx;
        As[kq * 4 + 1][row] = vy;
        As[kq * 4 + 2][row] = vz;
        As[kq * 4 + 3][row] = ve;
        Bs[kq * 4 + 0][row] = bv.x;
        Bs[kq * 4 + 1][row] = bv.y;
        Bs[kq * 4 + 2][row] = bv.z;
        Bs[kq * 4 + 3][row] = bv.w;
        __syncthreads();

#pragma unroll
        for (int kk = 0; kk < 16; ++kk) {
            const float4 a4 = *(const float4*)&As[kk][ty * 4];
            const float4 b4 = *(const float4*)&Bs[kk][tx * 4];
            const float av[4] = {a4.x, a4.y, a4.z, a4.w};
            const float bw[4] = {b4.x, b4.y, b4.z, b4.w};
#pragma unroll
            for (int u = 0; u < 4; ++u)
#pragma unroll
                for (int v = 0; v < 4; ++v)
                    acc[u][v] = fmaf(av[u], bw[v], acc[u][v]);
        }
    }

#pragma unroll
    for (int u = 0; u < 4; ++u) {
        float4 o4 = make_float4(acc[u][0], acc[u][1], acc[u][2], acc[u][3]);
        *(float4*)(C + (size_t)(m0 + ty * 4 + u) * N_DIM + n0 + tx * 4) = o4;
    }
}

// ---------------------------------------------------------------------------
extern "C" void kernel_launch(void* const* d_in, const int* in_sizes, int n_in,
                              void* d_out, int out_size, void* d_ws, size_t ws_size,
                              hipStream_t stream) {
    const float* x      = (const float*)d_in[0];  // (4096, 512, 3)
    const float* weight = (const float*)d_in[1];  // (512, 512)
    const float* action = (const float*)d_in[2];  // (512, 512, 8)
    const float* e0     = (const float*)d_in[3];  // (512, 1)
    float* out = (float*)d_out;                   // (4096, 512, 3)
    float* Bw  = (float*)d_ws;                    // N_DIM*K_DIM floats = 12.6 MB

    hipLaunchKernelGGL(build_w, dim3((O_DIM * I_DIM) / 256), dim3(256), 0, stream,
                       weight, action, Bw);
    hipLaunchKernelGGL(gemm_f32, dim3(N_DIM / 64, B_DIM / 64), dim3(256), 0, stream,
                       x, e0, Bw, out);
}

// Round 2
// 70.407 us; speedup vs baseline: 5.3049x; 5.3049x over previous
//
#include <hip/hip_runtime.h>
#include <hip/hip_bf16.h>

// ---------------------------------------------------------------------------
// PGAConjugateLinear as bf16 MFMA GEMM.
//   out[b, o*3+p] = sum_k A[b][k] * Bw[o*3+p][k],  k = i*4 + r
//   A[b][i*4+r] = (x[b,i,0], x[b,i,1], x[b,i,2], e0[i])  (bf16, packed)
//   Bw[n][k]    = weight[o,i] * sandwich-matrix[p][r]    (bf16, B^T layout)
// GEMM: M=4096, N=1536, K=2048. 128x128x32 tile, 4 waves, 16x16x32 MFMA,
// global_load_lds width-16 staging (m97 structure).
// ---------------------------------------------------------------------------

#define B_DIM 4096
#define I_DIM 512
#define O_DIM 512
#define N_DIM (O_DIM * 3)   // 1536
#define K_DIM (I_DIM * 4)   // 2048

typedef __attribute__((ext_vector_type(8))) short bf16x8;   // 8 bf16 (4 VGPRs)
typedef __attribute__((ext_vector_type(4))) float f32x4;    // MFMA acc

__device__ __forceinline__ unsigned short f2bf(float f) {
    unsigned u = __float_as_uint(f);
    unsigned r = (u + 0x7fffu + ((u >> 16) & 1u)) >> 16;  // RNE
    return (unsigned short)r;
}

__device__ __forceinline__ void gload_lds16(const void* g, void* l) {
    __builtin_amdgcn_global_load_lds(
        (const __attribute__((address_space(1))) unsigned*)g,
        (__attribute__((address_space(3))) unsigned*)l, 16, 0, 0);
}

// Cayley table for Cl(3,0,1), metric [0,1,1,1], reference blade order.
struct Cayley {
    float M[16][16][16];
    float rev[16];
    constexpr Cayley() : M{}, rev{} {
        const unsigned masks[16] = {0u, 1u, 2u, 4u, 8u, 3u, 5u, 9u, 6u, 10u,
                                    12u, 7u, 11u, 13u, 14u, 15u};
        int idx_of[16] = {};
        for (int i = 0; i < 16; ++i) idx_of[masks[i]] = i;
        const int metric[4] = {0, 1, 1, 1};
        for (int i = 0; i < 16; ++i) {
            unsigned a = masks[i];
            for (int j = 0; j < 16; ++j) {
                unsigned b = masks[j];
                int swaps = 0;
                for (int jb = 0; jb < 4; ++jb)
                    if ((b >> jb) & 1u)
                        for (int ia = jb + 1; ia < 4; ++ia)
                            if ((a >> ia) & 1u) ++swaps;
                int sign = (swaps & 1) ? -1 : 1;
                unsigned common = a & b;
                for (int g = 0; g < 4; ++g)
                    if ((common >> g) & 1u) sign *= metric[g];
                if (sign != 0) M[i][j][idx_of[a ^ b]] += (float)sign;
            }
            int grade = 0;
            for (int g = 0; g < 4; ++g) grade += (int)((a >> g) & 1u);
            rev[i] = ((grade * (grade - 1) / 2) % 2) ? -1.f : 1.f;
        }
    }
};
constexpr Cayley CAY{};

// ---------------------------------------------------------------------------
// Stage 1a: Bw[(o*3+p)][i*4+r] (bf16). One thread per (o,i); Cayley indices
// are compile-time so M folds to its sparse +-1 pattern.
// ---------------------------------------------------------------------------
__global__ __launch_bounds__(256) void build_w(const float* __restrict__ weight,
                                               const float* __restrict__ action,
                                               unsigned short* __restrict__ Bw) {
    const int t = blockIdx.x * 256 + threadIdx.x;   // t = o*512 + i
    const int o = t >> 9;
    const int i = t & 511;

    float a[8];
    const float* ap = action + (size_t)t * 8;
#pragma unroll
    for (int j = 0; j < 8; ++j) a[j] = ap[j];

    float kv[16], kr[16];
#pragma unroll
    for (int j = 0; j < 16; ++j) { kv[j] = 0.f; kr[j] = 0.f; }
    constexpr int AB[8] = {0, 5, 6, 7, 8, 9, 10, 15};
#pragma unroll
    for (int j = 0; j < 8; ++j) {
        kv[AB[j]] = a[j];
        kr[AB[j]] = a[j] * CAY.rev[AB[j]];
    }

    constexpr int PB[3] = {11, 12, 13};
    constexpr int RB[4] = {11, 12, 13, 14};

    float Am[3][16];
#pragma unroll
    for (int pp = 0; pp < 3; ++pp)
#pragma unroll
        for (int q = 0; q < 16; ++q) {
            float s = 0.f;
#pragma unroll
            for (int tt = 0; tt < 16; ++tt) s += CAY.M[q][PB[pp]][tt] * kr[tt];
            Am[pp][q] = s;
        }

    float Bm[16][4];
#pragma unroll
    for (int q = 0; q < 16; ++q)
#pragma unroll
        for (int rr = 0; rr < 4; ++rr) {
            float s = 0.f;
#pragma unroll
            for (int m = 0; m < 16; ++m) s += CAY.M[m][q][RB[rr]] * kv[m];
            Bm[q][rr] = s;
        }

    const float w = weight[t];
#pragma unroll
    for (int pp = 0; pp < 3; ++pp) {
        float r0 = 0.f, r1 = 0.f, r2 = 0.f, r3 = 0.f;
#pragma unroll
        for (int q = 0; q < 16; ++q) {
            r0 += Am[pp][q] * Bm[q][0];
            r1 += Am[pp][q] * Bm[q][1];
            r2 += Am[pp][q] * Bm[q][2];
            r3 += Am[pp][q] * Bm[q][3];
        }
        ushort4 o4;
        o4.x = f2bf(w * r0); o4.y = f2bf(w * r1);
        o4.z = f2bf(w * r2); o4.w = f2bf(w * r3);
        *(ushort4*)(Bw + (size_t)(o * 3 + pp) * K_DIM + i * 4) = o4;  // 8B coalesced
    }
}

// ---------------------------------------------------------------------------
// Stage 1b: pack A[b][i*4+r] = (x0,x1,x2,e0) in bf16. Thread handles 4 i's:
// 3 aligned float4 loads (48B per thread), one 32B store.
// ---------------------------------------------------------------------------
__global__ __launch_bounds__(256) void pack_x(const float* __restrict__ x,
                                              const float* __restrict__ e0,
                                              unsigned short* __restrict__ A) {
    const int t = blockIdx.x * 256 + threadIdx.x;   // 4096*128 threads
    const int b = t >> 7, ig = t & 127;             // ig: group of 4 i's

    const float4* xp = (const float4*)(x + (size_t)b * (I_DIM * 3) + ig * 12);
    const float4 v0 = xp[0], v1 = xp[1], v2 = xp[2];
    const float xs[12] = {v0.x, v0.y, v0.z, v0.w, v1.x, v1.y, v1.z, v1.w,
                          v2.x, v2.y, v2.z, v2.w};
    const float4 ev = *(const float4*)(e0 + ig * 4);
    const float es[4] = {ev.x, ev.y, ev.z, ev.w};

    unsigned short ov[16];
#pragma unroll
    for (int q = 0; q < 4; ++q) {
        ov[q * 4 + 0] = f2bf(xs[q * 3 + 0]);
        ov[q * 4 + 1] = f2bf(xs[q * 3 + 1]);
        ov[q * 4 + 2] = f2bf(xs[q * 3 + 2]);
        ov[q * 4 + 3] = f2bf(es[q]);
    }
    uint4* dst = (uint4*)(A + (size_t)b * K_DIM + ig * 16);  // 32B aligned
    dst[0] = ((const uint4*)ov)[0];
    dst[1] = ((const uint4*)ov)[1];
}

// ---------------------------------------------------------------------------
// Stage 2: C[m][n] = sum_k A[m][k]*Bw[n][k].  m97 structure:
// 128x128 tile, BK=32, 4 waves (2x2), each wave 64x64 = 4x4 16x16x32 MFMA.
// ---------------------------------------------------------------------------
__global__ __launch_bounds__(256) void gemm_bf16(const unsigned short* __restrict__ A,
                                                 const unsigned short* __restrict__ Bw,
                                                 float* __restrict__ C) {
    __shared__ unsigned short As[128 * 32];   // row-major [128][32], 8 KB
    __shared__ unsigned short Bs[128 * 32];

    const int tid = threadIdx.x;
    const int wave = tid >> 6, lane = tid & 63;
    const int m0 = blockIdx.y * 128, n0 = blockIdx.x * 128;
    const int wr = wave >> 1, wc = wave & 1;          // 2x2 wave grid

    // staging: 8 chunks of 16 rows x 32 cols (1024B); wave w owns chunks 2w,2w+1.
    // lane l -> row (chunk*16 + l/4), col (l%4)*8; LDS dest = base + lane*16B.
    const int srow = wave * 32 + (lane >> 2);
    const int scol = (lane & 3) * 8;
    const unsigned short* gA0 = A + (size_t)(m0 + srow) * K_DIM + scol;
    const unsigned short* gA1 = gA0 + 16 * K_DIM;
    const unsigned short* gB0 = Bw + (size_t)(n0 + srow) * K_DIM + scol;
    const unsigned short* gB1 = gB0 + 16 * K_DIM;
    unsigned short* lA0 = &As[wave * 1024];
    unsigned short* lA1 = lA0 + 512;
    unsigned short* lB0 = &Bs[wave * 1024];
    unsigned short* lB1 = lB0 + 512;

    // ds_read fragment addressing: row = tile_row + (lane&15), k = (lane>>4)*8
    const int frow = lane & 15;
    const int fk = (lane >> 4) * 8;

    f32x4 acc[4][4] = {};

    for (int k0 = 0; k0 < K_DIM; k0 += 32) {
        gload_lds16(gA0 + k0, lA0);
        gload_lds16(gA1 + k0, lA1);
        gload_lds16(gB0 + k0, lB0);
        gload_lds16(gB1 + k0, lB1);
        __syncthreads();   // drains vmcnt; tiles visible to all waves

        bf16x8 af[4], bf[4];
#pragma unroll
        for (int mi = 0; mi < 4; ++mi)
            af[mi] = *(const bf16x8*)&As[(wr * 64 + mi * 16 + frow) * 32 + fk];
#pragma unroll
        for (int ni = 0; ni < 4; ++ni)
            bf[ni] = *(const bf16x8*)&Bs[(wc * 64 + ni * 16 + frow) * 32 + fk];
#pragma unroll
        for (int mi = 0; mi < 4; ++mi)
#pragma unroll
            for (int ni = 0; ni < 4; ++ni)
                acc[mi][ni] = __builtin_amdgcn_mfma_f32_16x16x32_bf16(
                    af[mi], bf[ni], acc[mi][ni], 0, 0, 0);
        __syncthreads();   // compute done before next stage overwrites
    }

    // epilogue: C/D layout col = lane&15, row = (lane>>4)*4 + j
    const int crow = (lane >> 4) * 4;
    const int ccol = lane & 15;
#pragma unroll
    for (int mi = 0; mi < 4; ++mi)
#pragma unroll
        for (int ni = 0; ni < 4; ++ni) {
            float* cp = C + (size_t)(m0 + wr * 64 + mi * 16 + crow) * N_DIM
                        + n0 + wc * 64 + ni * 16 + ccol;
#pragma unroll
            for (int j = 0; j < 4; ++j) cp[(size_t)j * N_DIM] = acc[mi][ni][j];
        }
}

// ---------------------------------------------------------------------------
extern "C" void kernel_launch(void* const* d_in, const int* in_sizes, int n_in,
                              void* d_out, int out_size, void* d_ws, size_t ws_size,
                              hipStream_t stream) {
    const float* x      = (const float*)d_in[0];  // (4096, 512, 3)
    const float* weight = (const float*)d_in[1];  // (512, 512)
    const float* action = (const float*)d_in[2];  // (512, 512, 8)
    const float* e0     = (const float*)d_in[3];  // (512, 1)
    float* out = (float*)d_out;                   // (4096, 512, 3)

    unsigned short* Bw = (unsigned short*)d_ws;                   // N*K bf16 = 6.3 MB
    unsigned short* Ap = Bw + (size_t)N_DIM * K_DIM;              // M*K bf16 = 16.8 MB

    hipLaunchKernelGGL(build_w, dim3((O_DIM * I_DIM) / 256), dim3(256), 0, stream,
                       weight, action, Bw);
    hipLaunchKernelGGL(pack_x, dim3((B_DIM * 128) / 256), dim3(256), 0, stream,
                       x, e0, Ap);
    hipLaunchKernelGGL(gemm_bf16, dim3(N_DIM / 128, B_DIM / 128), dim3(256), 0, stream,
                       Ap, Bw, out);
}

// Round 3
// 52.653 us; speedup vs baseline: 7.0937x; 1.3372x over previous
//
#include <hip/hip_runtime.h>
#include <hip/hip_bf16.h>

// ---------------------------------------------------------------------------
// PGAConjugateLinear as bf16 MFMA GEMM + bias.
//   out[b, n=o*3+p] = sum_{k=i*3+r} A[b][k] * Bw[n][k]  +  bias[n]
//   A[b][k]  = bf16(x[b][k])              (x is (4096,512,3) contiguous!)
//   Bw[n][k] = weight[o,i] * T_oi[p][r]   (bf16, B^T layout, r in 0..2)
//   bias[n]  = sum_i weight[o,i] * T_oi[p][3] * e0[i]   (fp32, via atomics)
// GEMM: M=4096, N=1536, K=1536. Tile 64x128, BK=64, 4 waves, 16x16x32 MFMA.
// Grid = 64*12 = 768 blocks = exactly 3 blocks/CU (balanced), XCD-chunked.
// LDS XOR-swizzled both sides (linear gload_lds dest + pre-swizzled global
// source + swizzled ds_read) -> conflict-free b128 reads.
// ---------------------------------------------------------------------------

#define B_DIM 4096
#define I_DIM 512
#define O_DIM 512
#define N_DIM (O_DIM * 3)   // 1536
#define K_DIM (I_DIM * 3)   // 1536

typedef __attribute__((ext_vector_type(8))) short bf16x8;
typedef __attribute__((ext_vector_type(4))) float f32x4;

__device__ __forceinline__ unsigned short f2bf(float f) {
    unsigned u = __float_as_uint(f);
    unsigned r = (u + 0x7fffu + ((u >> 16) & 1u)) >> 16;  // RNE
    return (unsigned short)r;
}

__device__ __forceinline__ void gload_lds16(const void* g, void* l) {
    __builtin_amdgcn_global_load_lds(
        (const __attribute__((address_space(1))) unsigned*)g,
        (__attribute__((address_space(3))) unsigned*)l, 16, 0, 0);
}

// Cayley table for Cl(3,0,1), metric [0,1,1,1], reference blade order.
struct Cayley {
    float M[16][16][16];
    float rev[16];
    constexpr Cayley() : M{}, rev{} {
        const unsigned masks[16] = {0u, 1u, 2u, 4u, 8u, 3u, 5u, 9u, 6u, 10u,
                                    12u, 7u, 11u, 13u, 14u, 15u};
        int idx_of[16] = {};
        for (int i = 0; i < 16; ++i) idx_of[masks[i]] = i;
        const int metric[4] = {0, 1, 1, 1};
        for (int i = 0; i < 16; ++i) {
            unsigned a = masks[i];
            for (int j = 0; j < 16; ++j) {
                unsigned b = masks[j];
                int swaps = 0;
                for (int jb = 0; jb < 4; ++jb)
                    if ((b >> jb) & 1u)
                        for (int ia = jb + 1; ia < 4; ++ia)
                            if ((a >> ia) & 1u) ++swaps;
                int sign = (swaps & 1) ? -1 : 1;
                unsigned common = a & b;
                for (int g = 0; g < 4; ++g)
                    if ((common >> g) & 1u) sign *= metric[g];
                if (sign != 0) M[i][j][idx_of[a ^ b]] += (float)sign;
            }
            int grade = 0;
            for (int g = 0; g < 4; ++g) grade += (int)((a >> g) & 1u);
            rev[i] = ((grade * (grade - 1) / 2) % 2) ? -1.f : 1.f;
        }
    }
};
constexpr Cayley CAY{};

// ---------------------------------------------------------------------------
// Stage 1a: Bw[n][k] (bf16, r=0..2 only) + bias[n] (fp32 atomics, r=3 * e0).
// One thread per (o,i); Cayley indices compile-time -> sparse +-1 folding.
// ---------------------------------------------------------------------------
__global__ __launch_bounds__(256) void build_w(const float* __restrict__ weight,
                                               const float* __restrict__ action,
                                               const float* __restrict__ e0,
                                               unsigned short* __restrict__ Bw,
                                               float* __restrict__ bias) {
    const int t = blockIdx.x * 256 + threadIdx.x;   // t = o*512 + i
    const int o = t >> 9;
    const int i = t & 511;
    const int lane = threadIdx.x & 63;

    float a[8];
    const float* ap = action + (size_t)t * 8;
#pragma unroll
    for (int j = 0; j < 8; ++j) a[j] = ap[j];

    float kv[16], kr[16];
#pragma unroll
    for (int j = 0; j < 16; ++j) { kv[j] = 0.f; kr[j] = 0.f; }
    constexpr int AB[8] = {0, 5, 6, 7, 8, 9, 10, 15};
#pragma unroll
    for (int j = 0; j < 8; ++j) {
        kv[AB[j]] = a[j];
        kr[AB[j]] = a[j] * CAY.rev[AB[j]];
    }

    constexpr int PB[3] = {11, 12, 13};
    constexpr int RB[4] = {11, 12, 13, 14};

    float Am[3][16];
#pragma unroll
    for (int pp = 0; pp < 3; ++pp)
#pragma unroll
        for (int q = 0; q < 16; ++q) {
            float s = 0.f;
#pragma unroll
            for (int tt = 0; tt < 16; ++tt) s += CAY.M[q][PB[pp]][tt] * kr[tt];
            Am[pp][q] = s;
        }

    float Bm[16][4];
#pragma unroll
    for (int q = 0; q < 16; ++q)
#pragma unroll
        for (int rr = 0; rr < 4; ++rr) {
            float s = 0.f;
#pragma unroll
            for (int m = 0; m < 16; ++m) s += CAY.M[m][q][RB[rr]] * kv[m];
            Bm[q][rr] = s;
        }

    const float w = weight[t];
    const float e0i = e0[i];
#pragma unroll
    for (int pp = 0; pp < 3; ++pp) {
        float r0 = 0.f, r1 = 0.f, r2 = 0.f, r3 = 0.f;
#pragma unroll
        for (int q = 0; q < 16; ++q) {
            r0 += Am[pp][q] * Bm[q][0];
            r1 += Am[pp][q] * Bm[q][1];
            r2 += Am[pp][q] * Bm[q][2];
            r3 += Am[pp][q] * Bm[q][3];
        }
        unsigned short* bp = Bw + (size_t)(o * 3 + pp) * K_DIM + i * 3;
        bp[0] = f2bf(w * r0);
        bp[1] = f2bf(w * r1);
        bp[2] = f2bf(w * r2);
        // bias contribution: wave-reduce (same o across the wave), one atomic
        float s = w * r3 * e0i;
#pragma unroll
        for (int off = 32; off; off >>= 1) s += __shfl_down(s, off, 64);
        if (lane == 0) atomicAdd(bias + o * 3 + pp, s);
    }
}

// ---------------------------------------------------------------------------
// Stage 1b: A = bf16(x), pure flat cast (k=i*3+r is exactly x's layout).
// ---------------------------------------------------------------------------
__global__ __launch_bounds__(256) void pack_x(const float* __restrict__ x,
                                              unsigned short* __restrict__ A) {
    const size_t t = (size_t)blockIdx.x * 256 + threadIdx.x;  // 786432 threads
    const float4* xp = (const float4*)(x + t * 8);
    const float4 v0 = xp[0], v1 = xp[1];
    const float xs[8] = {v0.x, v0.y, v0.z, v0.w, v1.x, v1.y, v1.z, v1.w};
    unsigned short ov[8];
#pragma unroll
    for (int q = 0; q < 8; ++q) ov[q] = f2bf(xs[q]);
    *(uint4*)(A + t * 8) = *(const uint4*)ov;   // 16B store
}

// ---------------------------------------------------------------------------
// Stage 2: C[m][n] = sum_k A[m][k]*Bw[n][k] + bias[n].
// Tile 64x128, BK=64, 4 waves (2x2, each 32x64), 16 MFMA / K-step / wave.
// ---------------------------------------------------------------------------
__global__ __launch_bounds__(256) void gemm_bf16(const unsigned short* __restrict__ A,
                                                 const unsigned short* __restrict__ Bw,
                                                 const float* __restrict__ bias,
                                                 float* __restrict__ C) {
    __shared__ unsigned short As[64 * 64];    //  8 KB, [64][64] (+XOR swizzle)
    __shared__ unsigned short Bs[128 * 64];   // 16 KB, [128][64]

    const int tid = threadIdx.x;
    const int wave = tid >> 6, lane = tid & 63;

    // XCD-chunked bijective swizzle (768 % 8 == 0), m-tile-major so each
    // XCD's 96 consecutive tiles share B panels (L2-resident ~4.6MB).
    const int bid = blockIdx.x;
    const int swz = (bid & 7) * 96 + (bid >> 3);
    const int mt = swz / 12, nt = swz - mt * 12;
    const int m0 = mt * 64, n0 = nt * 128;
    const int wr = wave >> 1, wc = wave & 1;

    // --- staging: 16B segs; seg s -> LDS byte s*16 (linear), global col-seg
    // (s&7)^(row&7)  [both-sides swizzle: LDS slot j holds global seg j^(row&7)]
    const int sA0 = tid, sA1 = tid + 256;              // A: 512 segs (64 rows x 8)
    const unsigned short* aSrc0 =
        A + (size_t)(m0 + (sA0 >> 3)) * K_DIM + (((sA0 & 7) ^ ((sA0 >> 3) & 7)) * 8);
    const unsigned short* aSrc1 =
        A + (size_t)(m0 + (sA1 >> 3)) * K_DIM + (((sA1 & 7) ^ ((sA1 >> 3) & 7)) * 8);
    unsigned short* aDst0 = &As[(size_t)(0 * 256 + wave * 64) * 8];
    unsigned short* aDst1 = &As[(size_t)(1 * 256 + wave * 64) * 8];

    const unsigned short* bSrc[4];
    unsigned short* bDst[4];
#pragma unroll
    for (int q = 0; q < 4; ++q) {
        const int s = tid + q * 256;                   // B: 1024 segs (128 rows x 8)
        bSrc[q] = Bw + (size_t)(n0 + (s >> 3)) * K_DIM +
                  (((s & 7) ^ ((s >> 3) & 7)) * 8);
        bDst[q] = &Bs[(size_t)(q * 256 + wave * 64) * 8];
    }

    // --- fragment read offsets (swizzled): row r, global col-seg g ->
    // elem = r*64 + (g^(r&7))*8
    const int frow = lane & 15;
    const int g0 = lane >> 4;      // col-seg within K-half (g = g0 + kh*4)

    f32x4 acc[2][4] = {};

    for (int k0 = 0; k0 < K_DIM; k0 += 64) {
        gload_lds16(aSrc0 + k0, aDst0);
        gload_lds16(aSrc1 + k0, aDst1);
#pragma unroll
        for (int q = 0; q < 4; ++q) gload_lds16(bSrc[q] + k0, bDst[q]);
        __syncthreads();

        bf16x8 af[2][2], bf[2][4];
#pragma unroll
        for (int kh = 0; kh < 2; ++kh) {
#pragma unroll
            for (int mi = 0; mi < 2; ++mi) {
                const int r = wr * 32 + mi * 16 + frow;
                af[kh][mi] = *(const bf16x8*)&As[r * 64 + ((g0 + kh * 4) ^ (r & 7)) * 8];
            }
#pragma unroll
            for (int ni = 0; ni < 4; ++ni) {
                const int r = wc * 64 + ni * 16 + frow;
                bf[kh][ni] = *(const bf16x8*)&Bs[r * 64 + ((g0 + kh * 4) ^ (r & 7)) * 8];
            }
        }
#pragma unroll
        for (int kh = 0; kh < 2; ++kh)
#pragma unroll
            for (int mi = 0; mi < 2; ++mi)
#pragma unroll
                for (int ni = 0; ni < 4; ++ni)
                    acc[mi][ni] = __builtin_amdgcn_mfma_f32_16x16x32_bf16(
                        af[kh][mi], bf[kh][ni], acc[mi][ni], 0, 0, 0);
        __syncthreads();
    }

    // epilogue: C/D layout col = lane&15, row = (lane>>4)*4 + j; add bias[n]
    const int crow = (lane >> 4) * 4;
    const int ccol = lane & 15;
#pragma unroll
    for (int mi = 0; mi < 2; ++mi)
#pragma unroll
        for (int ni = 0; ni < 4; ++ni) {
            const int n = n0 + wc * 64 + ni * 16 + ccol;
            const float bv = bias[n];
            float* cp = C + (size_t)(m0 + wr * 32 + mi * 16 + crow) * N_DIM + n;
#pragma unroll
            for (int j = 0; j < 4; ++j) cp[(size_t)j * N_DIM] = acc[mi][ni][j] + bv;
        }
}

// ---------------------------------------------------------------------------
extern "C" void kernel_launch(void* const* d_in, const int* in_sizes, int n_in,
                              void* d_out, int out_size, void* d_ws, size_t ws_size,
                              hipStream_t stream) {
    const float* x      = (const float*)d_in[0];  // (4096, 512, 3)
    const float* weight = (const float*)d_in[1];  // (512, 512)
    const float* action = (const float*)d_in[2];  // (512, 512, 8)
    const float* e0     = (const float*)d_in[3];  // (512, 1)
    float* out = (float*)d_out;                   // (4096, 512, 3)

    unsigned short* Bw = (unsigned short*)d_ws;                    // 1536*1536 bf16 = 4.7 MB
    unsigned short* Ap = Bw + (size_t)N_DIM * K_DIM;               // 4096*1536 bf16 = 12.6 MB
    float* bias = (float*)(Ap + (size_t)B_DIM * K_DIM);            // 1536 f32

    hipMemsetAsync(bias, 0, N_DIM * sizeof(float), stream);
    hipLaunchKernelGGL(build_w, dim3((O_DIM * I_DIM) / 256), dim3(256), 0, stream,
                       weight, action, e0, Bw, bias);
    hipLaunchKernelGGL(pack_x, dim3((B_DIM * K_DIM / 8) / 256), dim3(256), 0, stream,
                       x, Ap);
    hipLaunchKernelGGL(gemm_bf16, dim3(768), dim3(256), 0, stream,
                       Ap, Bw, bias, out);
}

// Round 4
// 50.997 us; speedup vs baseline: 7.3241x; 1.0325x over previous
//
#include <hip/hip_runtime.h>
#include <hip/hip_bf16.h>

// ---------------------------------------------------------------------------
// PGAConjugateLinear as bf16 MFMA GEMM + bias.
//   out[b, n=o*3+p] = sum_{k=i*3+r} A[b][k] * Bw[n][k]  +  bias[n]
//   A[b][k]  = bf16(x[b][k])              (x is (4096,512,3) contiguous)
//   Bw[n][k] = weight[o,i] * T_oi[p][r]   (bf16, B^T layout, r in 0..2)
//   bias[n]  = sum_i weight[o,i] * T_oi[p][3] * e0[i]   (fp32, wave-reduced)
// GEMM: M=4096, N=1536, K=1536. Tile 64x128, BK=64, 4 waves, 16x16x32 MFMA.
// Grid 768 = exactly 3 blocks/CU; XCD-chunked swizzle; LDS XOR-swizzle both
// sides; DOUBLE-BUFFERED LDS: stage(t+1) issued before compute(t), one
// __syncthreads per K-step (drain lands after MFMAs, not before).
// ---------------------------------------------------------------------------

#define B_DIM 4096
#define I_DIM 512
#define O_DIM 512
#define N_DIM (O_DIM * 3)   // 1536
#define K_DIM (I_DIM * 3)   // 1536
#define NT (K_DIM / 64)     // 24 K-steps

typedef __attribute__((ext_vector_type(8))) short bf16x8;
typedef __attribute__((ext_vector_type(4))) float f32x4;

__device__ __forceinline__ unsigned short f2bf(float f) {
    unsigned u = __float_as_uint(f);
    unsigned r = (u + 0x7fffu + ((u >> 16) & 1u)) >> 16;  // RNE
    return (unsigned short)r;
}

__device__ __forceinline__ void gload_lds16(const void* g, void* l) {
    __builtin_amdgcn_global_load_lds(
        (const __attribute__((address_space(1))) unsigned*)g,
        (__attribute__((address_space(3))) unsigned*)l, 16, 0, 0);
}

// Cayley table for Cl(3,0,1), metric [0,1,1,1], reference blade order.
struct Cayley {
    float M[16][16][16];
    float rev[16];
    constexpr Cayley() : M{}, rev{} {
        const unsigned masks[16] = {0u, 1u, 2u, 4u, 8u, 3u, 5u, 9u, 6u, 10u,
                                    12u, 7u, 11u, 13u, 14u, 15u};
        int idx_of[16] = {};
        for (int i = 0; i < 16; ++i) idx_of[masks[i]] = i;
        const int metric[4] = {0, 1, 1, 1};
        for (int i = 0; i < 16; ++i) {
            unsigned a = masks[i];
            for (int j = 0; j < 16; ++j) {
                unsigned b = masks[j];
                int swaps = 0;
                for (int jb = 0; jb < 4; ++jb)
                    if ((b >> jb) & 1u)
                        for (int ia = jb + 1; ia < 4; ++ia)
                            if ((a >> ia) & 1u) ++swaps;
                int sign = (swaps & 1) ? -1 : 1;
                unsigned common = a & b;
                for (int g = 0; g < 4; ++g)
                    if ((common >> g) & 1u) sign *= metric[g];
                if (sign != 0) M[i][j][idx_of[a ^ b]] += (float)sign;
            }
            int grade = 0;
            for (int g = 0; g < 4; ++g) grade += (int)((a >> g) & 1u);
            rev[i] = ((grade * (grade - 1) / 2) % 2) ? -1.f : 1.f;
        }
    }
};
constexpr Cayley CAY{};

// ---------------------------------------------------------------------------
// Stage 1a: Bw[n][k] (bf16, r=0..2). One thread per (o,i); Cayley indices
// are compile-time so M folds to its sparse +-1 pattern.
// ---------------------------------------------------------------------------
__global__ __launch_bounds__(256) void build_w(const float* __restrict__ weight,
                                               const float* __restrict__ action,
                                               unsigned short* __restrict__ Bw) {
    const int t = blockIdx.x * 256 + threadIdx.x;   // t = o*512 + i
    const int o = t >> 9;
    const int i = t & 511;

    float a[8];
    const float* ap = action + (size_t)t * 8;
#pragma unroll
    for (int j = 0; j < 8; ++j) a[j] = ap[j];

    float kv[16], kr[16];
#pragma unroll
    for (int j = 0; j < 16; ++j) { kv[j] = 0.f; kr[j] = 0.f; }
    constexpr int AB[8] = {0, 5, 6, 7, 8, 9, 10, 15};
#pragma unroll
    for (int j = 0; j < 8; ++j) {
        kv[AB[j]] = a[j];
        kr[AB[j]] = a[j] * CAY.rev[AB[j]];
    }

    constexpr int PB[3] = {11, 12, 13};
    constexpr int RB[3] = {11, 12, 13};

    float Am[3][16];
#pragma unroll
    for (int pp = 0; pp < 3; ++pp)
#pragma unroll
        for (int q = 0; q < 16; ++q) {
            float s = 0.f;
#pragma unroll
            for (int tt = 0; tt < 16; ++tt) s += CAY.M[q][PB[pp]][tt] * kr[tt];
            Am[pp][q] = s;
        }

    float Bm[16][3];
#pragma unroll
    for (int q = 0; q < 16; ++q)
#pragma unroll
        for (int rr = 0; rr < 3; ++rr) {
            float s = 0.f;
#pragma unroll
            for (int m = 0; m < 16; ++m) s += CAY.M[m][q][RB[rr]] * kv[m];
            Bm[q][rr] = s;
        }

    const float w = weight[t];
#pragma unroll
    for (int pp = 0; pp < 3; ++pp) {
        float r0 = 0.f, r1 = 0.f, r2 = 0.f;
#pragma unroll
        for (int q = 0; q < 16; ++q) {
            r0 += Am[pp][q] * Bm[q][0];
            r1 += Am[pp][q] * Bm[q][1];
            r2 += Am[pp][q] * Bm[q][2];
        }
        unsigned short* bp = Bw + (size_t)(o * 3 + pp) * K_DIM + i * 3;
        bp[0] = f2bf(w * r0);
        bp[1] = f2bf(w * r1);
        bp[2] = f2bf(w * r2);
    }
}

// ---------------------------------------------------------------------------
// Stage 1b: bias[o*3+p] = sum_i weight[o,i]*T_oi[p][3]*e0[i].
// One wave per o; deterministic wave shuffle-reduce; no atomics, no memset.
// ---------------------------------------------------------------------------
__global__ __launch_bounds__(64) void build_bias(const float* __restrict__ weight,
                                                 const float* __restrict__ action,
                                                 const float* __restrict__ e0,
                                                 float* __restrict__ bias) {
    const int o = blockIdx.x;
    const int lane = threadIdx.x;
    constexpr int AB[8] = {0, 5, 6, 7, 8, 9, 10, 15};
    constexpr int PB[3] = {11, 12, 13};

    float s0 = 0.f, s1 = 0.f, s2 = 0.f;
#pragma unroll
    for (int ii = 0; ii < 8; ++ii) {
        const int i = lane + ii * 64;
        const int t = o * I_DIM + i;
        float a[8];
        const float* ap = action + (size_t)t * 8;
#pragma unroll
        for (int j = 0; j < 8; ++j) a[j] = ap[j];
        float kv[16], kr[16];
#pragma unroll
        for (int j = 0; j < 16; ++j) { kv[j] = 0.f; kr[j] = 0.f; }
#pragma unroll
        for (int j = 0; j < 8; ++j) {
            kv[AB[j]] = a[j];
            kr[AB[j]] = a[j] * CAY.rev[AB[j]];
        }
        float Bm3[16];
#pragma unroll
        for (int q = 0; q < 16; ++q) {
            float s = 0.f;
#pragma unroll
            for (int m = 0; m < 16; ++m) s += CAY.M[m][q][14] * kv[m];
            Bm3[q] = s;
        }
        float T3[3];
#pragma unroll
        for (int pp = 0; pp < 3; ++pp) {
            float acc = 0.f;
#pragma unroll
            for (int q = 0; q < 16; ++q) {
                float am = 0.f;
#pragma unroll
                for (int tt = 0; tt < 16; ++tt) am += CAY.M[q][PB[pp]][tt] * kr[tt];
                acc += am * Bm3[q];
            }
            T3[pp] = acc;
        }
        const float we = weight[t] * e0[i];
        s0 += we * T3[0];
        s1 += we * T3[1];
        s2 += we * T3[2];
    }
#pragma unroll
    for (int off = 32; off; off >>= 1) {
        s0 += __shfl_down(s0, off, 64);
        s1 += __shfl_down(s1, off, 64);
        s2 += __shfl_down(s2, off, 64);
    }
    if (lane == 0) {
        bias[o * 3 + 0] = s0;
        bias[o * 3 + 1] = s1;
        bias[o * 3 + 2] = s2;
    }
}

// ---------------------------------------------------------------------------
// Stage 1c: A = bf16(x), pure flat cast (k=i*3+r is exactly x's layout).
// ---------------------------------------------------------------------------
__global__ __launch_bounds__(256) void pack_x(const float* __restrict__ x,
                                              unsigned short* __restrict__ A) {
    const size_t t = (size_t)blockIdx.x * 256 + threadIdx.x;  // 786432 threads
    const float4* xp = (const float4*)(x + t * 8);
    const float4 v0 = xp[0], v1 = xp[1];
    const float xs[8] = {v0.x, v0.y, v0.z, v0.w, v1.x, v1.y, v1.z, v1.w};
    unsigned short ov[8];
#pragma unroll
    for (int q = 0; q < 8; ++q) ov[q] = f2bf(xs[q]);
    *(uint4*)(A + t * 8) = *(const uint4*)ov;   // 16B store
}

// ---------------------------------------------------------------------------
// Stage 2: C[m][n] = sum_k A[m][k]*Bw[n][k] + bias[n].
// Tile 64x128, BK=64, 4 waves (2x2, each 32x64). Double-buffered LDS with
// statically-named buffers (no alias -> no vmcnt drain before ds_read).
// ---------------------------------------------------------------------------
__global__ __launch_bounds__(256) void gemm_bf16(const unsigned short* __restrict__ A,
                                                 const unsigned short* __restrict__ Bw,
                                                 const float* __restrict__ bias,
                                                 float* __restrict__ C) {
    __shared__ unsigned short As0[64 * 64], As1[64 * 64];    // 8 KB each
    __shared__ unsigned short Bs0[128 * 64], Bs1[128 * 64];  // 16 KB each

    const int tid = threadIdx.x;
    const int wave = tid >> 6, lane = tid & 63;

    // XCD-chunked bijective swizzle (768 % 8 == 0), m-tile-major.
    const int bid = blockIdx.x;
    const int swz = (bid & 7) * 96 + (bid >> 3);
    const int mt = swz / 12, nt = swz - mt * 12;
    const int m0 = mt * 64, n0 = nt * 128;
    const int wr = wave >> 1, wc = wave & 1;

    // staging: 16B segs; seg s -> LDS byte s*16 (linear); global col-seg
    // = (s&7)^(row&7)   [both-sides XOR swizzle]
    const int sA0 = tid, sA1 = tid + 256;              // A: 512 segs
    const unsigned short* aSrc0 =
        A + (size_t)(m0 + (sA0 >> 3)) * K_DIM + (((sA0 & 7) ^ ((sA0 >> 3) & 7)) * 8);
    const unsigned short* aSrc1 =
        A + (size_t)(m0 + (sA1 >> 3)) * K_DIM + (((sA1 & 7) ^ ((sA1 >> 3) & 7)) * 8);
    const int aOff0 = (0 * 256 + wave * 64) * 8;       // LDS short-offsets
    const int aOff1 = (1 * 256 + wave * 64) * 8;

    const unsigned short* bSrc[4];
    int bOff[4];
#pragma unroll
    for (int q = 0; q < 4; ++q) {
        const int s = tid + q * 256;                   // B: 1024 segs
        bSrc[q] = Bw + (size_t)(n0 + (s >> 3)) * K_DIM +
                  (((s & 7) ^ ((s >> 3) & 7)) * 8);
        bOff[q] = (q * 256 + wave * 64) * 8;
    }

    // fragment read: row r, global col-seg g -> elem r*64 + (g^(r&7))*8
    const int frow = lane & 15;
    const int g0 = lane >> 4;

    f32x4 acc[2][4] = {};

#define STAGE(AS, BS, K0)                                   \
    do {                                                    \
        gload_lds16(aSrc0 + (K0), (AS) + aOff0);            \
        gload_lds16(aSrc1 + (K0), (AS) + aOff1);            \
        _Pragma("unroll")                                   \
        for (int q = 0; q < 4; ++q)                         \
            gload_lds16(bSrc[q] + (K0), (BS) + bOff[q]);    \
    } while (0)

#define COMPUTE(AS, BS)                                                        \
    do {                                                                       \
        bf16x8 af[2][2], bfr[2][4];                                            \
        _Pragma("unroll")                                                      \
        for (int kh = 0; kh < 2; ++kh) {                                       \
            _Pragma("unroll")                                                  \
            for (int mi = 0; mi < 2; ++mi) {                                   \
                const int r = wr * 32 + mi * 16 + frow;                        \
                af[kh][mi] =                                                   \
                    *(const bf16x8*)&(AS)[r * 64 + ((g0 + kh * 4) ^ (r & 7)) * 8]; \
            }                                                                  \
            _Pragma("unroll")                                                  \
            for (int ni = 0; ni < 4; ++ni) {                                   \
                const int r = wc * 64 + ni * 16 + frow;                        \
                bfr[kh][ni] =                                                  \
                    *(const bf16x8*)&(BS)[r * 64 + ((g0 + kh * 4) ^ (r & 7)) * 8]; \
            }                                                                  \
        }                                                                      \
        _Pragma("unroll")                                                      \
        for (int kh = 0; kh < 2; ++kh)                                         \
            _Pragma("unroll")                                                  \
            for (int mi = 0; mi < 2; ++mi)                                     \
                _Pragma("unroll")                                              \
                for (int ni = 0; ni < 4; ++ni)                                 \
                    acc[mi][ni] = __builtin_amdgcn_mfma_f32_16x16x32_bf16(     \
                        af[kh][mi], bfr[kh][ni], acc[mi][ni], 0, 0, 0);        \
    } while (0)

    STAGE(As0, Bs0, 0);
    __syncthreads();                       // buf0 ready

    for (int t = 0; t < NT - 2; t += 2) {
        STAGE(As1, Bs1, (t + 1) * 64);     // issue next-tile loads FIRST
        COMPUTE(As0, Bs0);                 // MFMA hides load latency
        __syncthreads();                   // drain (post-compute) + sync
        STAGE(As0, Bs0, (t + 2) * 64);
        COMPUTE(As1, Bs1);
        __syncthreads();
    }
    STAGE(As1, Bs1, (NT - 1) * 64);
    COMPUTE(As0, Bs0);
    __syncthreads();
    COMPUTE(As1, Bs1);

#undef STAGE
#undef COMPUTE

    // epilogue: C/D layout col = lane&15, row = (lane>>4)*4 + j; add bias[n]
    const int crow = (lane >> 4) * 4;
    const int ccol = lane & 15;
#pragma unroll
    for (int mi = 0; mi < 2; ++mi)
#pragma unroll
        for (int ni = 0; ni < 4; ++ni) {
            const int n = n0 + wc * 64 + ni * 16 + ccol;
            const float bv = bias[n];
            float* cp = C + (size_t)(m0 + wr * 32 + mi * 16 + crow) * N_DIM + n;
#pragma unroll
            for (int j = 0; j < 4; ++j) cp[(size_t)j * N_DIM] = acc[mi][ni][j] + bv;
        }
}

// ---------------------------------------------------------------------------
extern "C" void kernel_launch(void* const* d_in, const int* in_sizes, int n_in,
                              void* d_out, int out_size, void* d_ws, size_t ws_size,
                              hipStream_t stream) {
    const float* x      = (const float*)d_in[0];  // (4096, 512, 3)
    const float* weight = (const float*)d_in[1];  // (512, 512)
    const float* action = (const float*)d_in[2];  // (512, 512, 8)
    const float* e0     = (const float*)d_in[3];  // (512, 1)
    float* out = (float*)d_out;                   // (4096, 512, 3)

    unsigned short* Bw = (unsigned short*)d_ws;                 // 4.7 MB
    unsigned short* Ap = Bw + (size_t)N_DIM * K_DIM;            // 12.6 MB
    float* bias = (float*)(Ap + (size_t)B_DIM * K_DIM);         // 1536 f32

    hipLaunchKernelGGL(build_w, dim3((O_DIM * I_DIM) / 256), dim3(256), 0, stream,
                       weight, action, Bw);
    hipLaunchKernelGGL(build_bias, dim3(O_DIM), dim3(64), 0, stream,
                       weight, action, e0, bias);
    hipLaunchKernelGGL(pack_x, dim3((B_DIM * K_DIM / 8) / 256), dim3(256), 0, stream,
                       x, Ap);
    hipLaunchKernelGGL(gemm_bf16, dim3(768), dim3(256), 0, stream,
                       Ap, Bw, bias, out);
}

// Round 5
// 44.655 us; speedup vs baseline: 8.3642x; 1.1420x over previous
//
#include <hip/hip_runtime.h>
#include <hip/hip_bf16.h>

// ---------------------------------------------------------------------------
// PGAConjugateLinear as bf16 MFMA GEMM + bias.
//   out[b, n=o*3+p] = sum_{k=i*3+r} A[b][k] * Bw[n][k]  +  bias[n]
//   A[b][k]  = bf16(x[b][k])              (x is (4096,512,3) contiguous)
//   Bw[n][k] = weight[o,i] * T_oi[p][r]   (bf16, B^T layout, r in 0..2)
//   bias[n]  = sum_i weight[o,i] * T_oi[p][3] * e0[i]   (fp32, block-reduced)
// GEMM: M=4096, N=1536, K=1536. Tile 64x128, BK=64, EIGHT waves (2x4, each
// 32x32 out), 16x16x32 MFMA. Grid 768 = 3 blocks/CU -> 24 waves/CU (TLP to
// hide staging latency). Double-buffered LDS (48 KB), both-sides XOR swizzle,
// XCD-chunked block swizzle.
// ---------------------------------------------------------------------------

#define B_DIM 4096
#define I_DIM 512
#define O_DIM 512
#define N_DIM (O_DIM * 3)   // 1536
#define K_DIM (I_DIM * 3)   // 1536
#define NT (K_DIM / 64)     // 24 K-steps

typedef __attribute__((ext_vector_type(8))) short bf16x8;
typedef __attribute__((ext_vector_type(4))) float f32x4;

__device__ __forceinline__ unsigned short f2bf(float f) {
    unsigned u = __float_as_uint(f);
    unsigned r = (u + 0x7fffu + ((u >> 16) & 1u)) >> 16;  // RNE
    return (unsigned short)r;
}

__device__ __forceinline__ void gload_lds16(const void* g, void* l) {
    __builtin_amdgcn_global_load_lds(
        (const __attribute__((address_space(1))) unsigned*)g,
        (__attribute__((address_space(3))) unsigned*)l, 16, 0, 0);
}

// Cayley table for Cl(3,0,1), metric [0,1,1,1], reference blade order.
struct Cayley {
    float M[16][16][16];
    float rev[16];
    constexpr Cayley() : M{}, rev{} {
        const unsigned masks[16] = {0u, 1u, 2u, 4u, 8u, 3u, 5u, 9u, 6u, 10u,
                                    12u, 7u, 11u, 13u, 14u, 15u};
        int idx_of[16] = {};
        for (int i = 0; i < 16; ++i) idx_of[masks[i]] = i;
        const int metric[4] = {0, 1, 1, 1};
        for (int i = 0; i < 16; ++i) {
            unsigned a = masks[i];
            for (int j = 0; j < 16; ++j) {
                unsigned b = masks[j];
                int swaps = 0;
                for (int jb = 0; jb < 4; ++jb)
                    if ((b >> jb) & 1u)
                        for (int ia = jb + 1; ia < 4; ++ia)
                            if ((a >> ia) & 1u) ++swaps;
                int sign = (swaps & 1) ? -1 : 1;
                unsigned common = a & b;
                for (int g = 0; g < 4; ++g)
                    if ((common >> g) & 1u) sign *= metric[g];
                if (sign != 0) M[i][j][idx_of[a ^ b]] += (float)sign;
            }
            int grade = 0;
            for (int g = 0; g < 4; ++g) grade += (int)((a >> g) & 1u);
            rev[i] = ((grade * (grade - 1) / 2) % 2) ? -1.f : 1.f;
        }
    }
};
constexpr Cayley CAY{};

// ---------------------------------------------------------------------------
// Stage 1: one block per o. Bw rows (bf16) + bias[o*3+p] (fp32 block-reduce).
// Cayley indices compile-time -> sparse +-1 folding.
// ---------------------------------------------------------------------------
__global__ __launch_bounds__(256) void build_w(const float* __restrict__ weight,
                                               const float* __restrict__ action,
                                               const float* __restrict__ e0,
                                               unsigned short* __restrict__ Bw,
                                               float* __restrict__ bias) {
    const int o = blockIdx.x;
    const int tid = threadIdx.x;
    const int wave = tid >> 6, lane = tid & 63;
    __shared__ float red[4][3];

    constexpr int AB[8] = {0, 5, 6, 7, 8, 9, 10, 15};
    constexpr int PB[3] = {11, 12, 13};
    constexpr int RB[4] = {11, 12, 13, 14};

    float sb[3] = {0.f, 0.f, 0.f};

#pragma unroll
    for (int s = 0; s < 2; ++s) {
        const int i = tid * 2 + s;
        const int t = o * I_DIM + i;

        float a[8];
        const float* ap = action + (size_t)t * 8;
#pragma unroll
        for (int j = 0; j < 8; ++j) a[j] = ap[j];

        float kv[16], kr[16];
#pragma unroll
        for (int j = 0; j < 16; ++j) { kv[j] = 0.f; kr[j] = 0.f; }
#pragma unroll
        for (int j = 0; j < 8; ++j) {
            kv[AB[j]] = a[j];
            kr[AB[j]] = a[j] * CAY.rev[AB[j]];
        }

        float Am[3][16];
#pragma unroll
        for (int pp = 0; pp < 3; ++pp)
#pragma unroll
            for (int q = 0; q < 16; ++q) {
                float sum = 0.f;
#pragma unroll
                for (int tt = 0; tt < 16; ++tt) sum += CAY.M[q][PB[pp]][tt] * kr[tt];
                Am[pp][q] = sum;
            }

        float Bm[16][4];
#pragma unroll
        for (int q = 0; q < 16; ++q)
#pragma unroll
            for (int rr = 0; rr < 4; ++rr) {
                float sum = 0.f;
#pragma unroll
                for (int m = 0; m < 16; ++m) sum += CAY.M[m][q][RB[rr]] * kv[m];
                Bm[q][rr] = sum;
            }

        const float w = weight[t];
        const float e0i = e0[i];
#pragma unroll
        for (int pp = 0; pp < 3; ++pp) {
            float r0 = 0.f, r1 = 0.f, r2 = 0.f, r3 = 0.f;
#pragma unroll
            for (int q = 0; q < 16; ++q) {
                r0 += Am[pp][q] * Bm[q][0];
                r1 += Am[pp][q] * Bm[q][1];
                r2 += Am[pp][q] * Bm[q][2];
                r3 += Am[pp][q] * Bm[q][3];
            }
            unsigned short* bp = Bw + (size_t)(o * 3 + pp) * K_DIM + i * 3;
            bp[0] = f2bf(w * r0);
            bp[1] = f2bf(w * r1);
            bp[2] = f2bf(w * r2);
            sb[pp] += w * r3 * e0i;
        }
    }

    // block reduce bias (wave shuffle + LDS across 4 waves)
#pragma unroll
    for (int off = 32; off; off >>= 1) {
#pragma unroll
        for (int pp = 0; pp < 3; ++pp) sb[pp] += __shfl_down(sb[pp], off, 64);
    }
    if (lane == 0) {
#pragma unroll
        for (int pp = 0; pp < 3; ++pp) red[wave][pp] = sb[pp];
    }
    __syncthreads();
    if (tid == 0) {
#pragma unroll
        for (int pp = 0; pp < 3; ++pp)
            bias[o * 3 + pp] = red[0][pp] + red[1][pp] + red[2][pp] + red[3][pp];
    }
}

// ---------------------------------------------------------------------------
// Stage 2: A = bf16(x), pure flat cast (k=i*3+r is exactly x's layout).
// ---------------------------------------------------------------------------
__global__ __launch_bounds__(256) void pack_x(const float* __restrict__ x,
                                              unsigned short* __restrict__ A) {
    const size_t t = (size_t)blockIdx.x * 256 + threadIdx.x;  // 786432 threads
    const float4* xp = (const float4*)(x + t * 8);
    const float4 v0 = xp[0], v1 = xp[1];
    const float xs[8] = {v0.x, v0.y, v0.z, v0.w, v1.x, v1.y, v1.z, v1.w};
    unsigned short ov[8];
#pragma unroll
    for (int q = 0; q < 8; ++q) ov[q] = f2bf(xs[q]);
    *(uint4*)(A + t * 8) = *(const uint4*)ov;   // 16B store
}

// ---------------------------------------------------------------------------
// Stage 3: C[m][n] = sum_k A[m][k]*Bw[n][k] + bias[n].
// Tile 64x128, BK=64, 8 waves (2x4, each 32x32). Double-buffered LDS.
// ---------------------------------------------------------------------------
__global__ __launch_bounds__(512, 6) void gemm_bf16(
        const unsigned short* __restrict__ A,
        const unsigned short* __restrict__ Bw,
        const float* __restrict__ bias,
        float* __restrict__ C) {
    __shared__ unsigned short As0[64 * 64], As1[64 * 64];    //  8 KB each
    __shared__ unsigned short Bs0[128 * 64], Bs1[128 * 64];  // 16 KB each

    const int tid = threadIdx.x;
    const int wave = tid >> 6, lane = tid & 63;

    // XCD-chunked bijective swizzle (768 % 8 == 0), m-tile-major.
    const int bid = blockIdx.x;
    const int swz = (bid & 7) * 96 + (bid >> 3);
    const int mt = swz / 12, nt = swz - mt * 12;
    const int m0 = mt * 64, n0 = nt * 128;
    const int wr = wave >> 2, wc = wave & 3;     // 2x4 wave grid, 32x32 each

    // staging: 16B segs; seg s -> LDS byte s*16 (linear); global col-seg
    // = (s&7)^(row&7)   [both-sides XOR swizzle]
    const int sA = tid;                                  // A: 512 segs (1/thread)
    const unsigned short* aSrc =
        A + (size_t)(m0 + (sA >> 3)) * K_DIM + (((sA & 7) ^ ((sA >> 3) & 7)) * 8);
    const int aOff = tid * 16 / 2;                       // short offset = tid*8

    const unsigned short* bSrc[2];
    int bOff[2];
#pragma unroll
    for (int q = 0; q < 2; ++q) {
        const int s = tid + q * 512;                     // B: 1024 segs (2/thread)
        bSrc[q] = Bw + (size_t)(n0 + (s >> 3)) * K_DIM +
                  (((s & 7) ^ ((s >> 3) & 7)) * 8);
        bOff[q] = s * 8;
    }

    // fragment read: row r, global col-seg g -> elem r*64 + (g^(r&7))*8
    const int frow = lane & 15;
    const int g0 = lane >> 4;

    f32x4 acc[2][2] = {};

#define STAGE(AS, BS, K0)                                   \
    do {                                                    \
        gload_lds16(aSrc + (K0), (AS) + aOff);              \
        gload_lds16(bSrc[0] + (K0), (BS) + bOff[0]);        \
        gload_lds16(bSrc[1] + (K0), (BS) + bOff[1]);        \
    } while (0)

#define COMPUTE(AS, BS)                                                        \
    do {                                                                       \
        bf16x8 af[2][2], bfr[2][2];                                            \
        _Pragma("unroll")                                                      \
        for (int kh = 0; kh < 2; ++kh) {                                       \
            _Pragma("unroll")                                                  \
            for (int mi = 0; mi < 2; ++mi) {                                   \
                const int r = wr * 32 + mi * 16 + frow;                        \
                af[kh][mi] =                                                   \
                    *(const bf16x8*)&(AS)[r * 64 + ((g0 + kh * 4) ^ (r & 7)) * 8]; \
            }                                                                  \
            _Pragma("unroll")                                                  \
            for (int ni = 0; ni < 2; ++ni) {                                   \
                const int r = wc * 32 + ni * 16 + frow;                        \
                bfr[kh][ni] =                                                  \
                    *(const bf16x8*)&(BS)[r * 64 + ((g0 + kh * 4) ^ (r & 7)) * 8]; \
            }                                                                  \
        }                                                                      \
        _Pragma("unroll")                                                      \
        for (int kh = 0; kh < 2; ++kh)                                         \
            _Pragma("unroll")                                                  \
            for (int mi = 0; mi < 2; ++mi)                                     \
                _Pragma("unroll")                                              \
                for (int ni = 0; ni < 2; ++ni)                                 \
                    acc[mi][ni] = __builtin_amdgcn_mfma_f32_16x16x32_bf16(     \
                        af[kh][mi], bfr[kh][ni], acc[mi][ni], 0, 0, 0);        \
    } while (0)

    STAGE(As0, Bs0, 0);
    __syncthreads();                       // buf0 ready

    for (int t = 0; t < NT - 2; t += 2) {
        STAGE(As1, Bs1, (t + 1) * 64);     // issue next-tile loads FIRST
        COMPUTE(As0, Bs0);                 // MFMA + other waves hide latency
        __syncthreads();
        STAGE(As0, Bs0, (t + 2) * 64);
        COMPUTE(As1, Bs1);
        __syncthreads();
    }
    STAGE(As1, Bs1, (NT - 1) * 64);
    COMPUTE(As0, Bs0);
    __syncthreads();
    COMPUTE(As1, Bs1);

#undef STAGE
#undef COMPUTE

    // epilogue: C/D layout col = lane&15, row = (lane>>4)*4 + j; add bias[n]
    const int crow = (lane >> 4) * 4;
    const int ccol = lane & 15;
#pragma unroll
    for (int mi = 0; mi < 2; ++mi)
#pragma unroll
        for (int ni = 0; ni < 2; ++ni) {
            const int n = n0 + wc * 32 + ni * 16 + ccol;
            const float bv = bias[n];
            float* cp = C + (size_t)(m0 + wr * 32 + mi * 16 + crow) * N_DIM + n;
#pragma unroll
            for (int j = 0; j < 4; ++j) cp[(size_t)j * N_DIM] = acc[mi][ni][j] + bv;
        }
}

// ---------------------------------------------------------------------------
extern "C" void kernel_launch(void* const* d_in, const int* in_sizes, int n_in,
                              void* d_out, int out_size, void* d_ws, size_t ws_size,
                              hipStream_t stream) {
    const float* x      = (const float*)d_in[0];  // (4096, 512, 3)
    const float* weight = (const float*)d_in[1];  // (512, 512)
    const float* action = (const float*)d_in[2];  // (512, 512, 8)
    const float* e0     = (const float*)d_in[3];  // (512, 1)
    float* out = (float*)d_out;                   // (4096, 512, 3)

    unsigned short* Bw = (unsigned short*)d_ws;                 // 4.7 MB
    unsigned short* Ap = Bw + (size_t)N_DIM * K_DIM;            // 12.6 MB
    float* bias = (float*)(Ap + (size_t)B_DIM * K_DIM);         // 1536 f32

    hipLaunchKernelGGL(build_w, dim3(O_DIM), dim3(256), 0, stream,
                       weight, action, e0, Bw, bias);
    hipLaunchKernelGGL(pack_x, dim3((B_DIM * K_DIM / 8) / 256), dim3(256), 0, stream,
                       x, Ap);
    hipLaunchKernelGGL(gemm_bf16, dim3(768), dim3(512), 0, stream,
                       Ap, Bw, bias, out);
}